// Round 5
// baseline (119.650 us; speedup 1.0000x reference)
//
#include <hip/hip_runtime.h>
#include <math.h>

#define VOCABN 100000
#define EMBD 300
#define HID 128
#define NQ 32
#define NTOP 10

#define KPAD 320            // padded K: 10 chunks of 32
#define NCH 10
#define WK 32               // k per chunk
#define WCPAD 36            // LDS bf16 per col row (32 + 4 pad) -> 72B stride, 2-way banks
#define SC_ROWS 128         // rows per block (4 waves x 32 rows)
#define SC_NBLK ((VOCABN + SC_ROWS - 1) / SC_ROWS)   // 782

typedef __attribute__((ext_vector_type(8))) short bf16x8;
typedef __attribute__((ext_vector_type(4))) float f32x4;
typedef __attribute__((ext_vector_type(16))) float f32x16;
typedef __attribute__((ext_vector_type(4))) unsigned int u32x4;

__device__ __forceinline__ void split8(const f32x4 a, const f32x4 b,
                                       u32x4* hi, u32x4* lo) {
    float ef[8] = {a.x, a.y, a.z, a.w, b.x, b.y, b.z, b.w};
    unsigned int hw[8], lw[8];
#pragma unroll
    for (int j = 0; j < 8; ++j) {
        unsigned int u = __float_as_uint(ef[j]);
        hw[j] = u >> 16;
        float r = __uint_as_float(u & 0xffff0000u);
        lw[j] = __float_as_uint(ef[j] - r) >> 16;
    }
    *hi = (u32x4){hw[0] | (hw[1] << 16), hw[2] | (hw[3] << 16),
                  hw[4] | (hw[5] << 16), hw[6] | (hw[7] << 16)};
    *lo = (u32x4){lw[0] | (lw[1] << 16), lw[2] | (lw[3] << 16),
                  lw[4] | (lw[5] << 16), lw[6] | (lw[7] << 16)};
}

// ---------------- fused: histogram | qctx+qcb | W1a transpose+bf16-split ----------------
__global__ __launch_bounds__(256) void k_pre(const int* __restrict__ qterms,
                                             const int* __restrict__ fdocs, int nflat, int hblocks,
                                             const float* __restrict__ emb,
                                             const float* __restrict__ sW1,
                                             const float* __restrict__ sb1,
                                             int* __restrict__ counts,
                                             float* __restrict__ qctx,
                                             float* __restrict__ qcb,
                                             unsigned short* __restrict__ whi,
                                             unsigned short* __restrict__ wlo) {
    int t = threadIdx.x;
    int b = blockIdx.x;
    if (b < hblocks) {                       // histogram
        int i = b * 256 + t;
        if (i < nflat) atomicAdd(&counts[fdocs[i]], 1);
        return;
    }
    if (b == hblocks) {                      // query context + scorer bias
        __shared__ int qid[NQ];
        __shared__ float qc[EMBD];
        if (t < NQ) qid[t] = qterms[t];
        __syncthreads();
        for (int i = t; i < EMBD; i += 256) {
            float s = 0.f;
            for (int q = 0; q < NQ; ++q) s += emb[(long)qid[q] * EMBD + i];
            float v = s * (1.0f / NQ);
            qc[i] = v; qctx[i] = v;
        }
        __syncthreads();
        int col = t >> 1, half = t & 1;
        float a = 0.f;
        int k0 = half * 150;
        for (int k = k0; k < k0 + 150; ++k)
            a += qc[k] * sW1[(long)(EMBD + k) * HID + col];
        a += __shfl_xor(a, 1);
        if (half == 0) qcb[col] = a + sb1[col];
        return;
    }
    // W1a (rows 0..299) -> transposed [col][KPAD], zero-padded, bf16 hi/lo split
    int i = (b - hblocks - 1) * 256 + t;     // over HID*KPAD
    if (i < HID * KPAD) {
        int k = i >> 7, c = i & 127;
        unsigned int hi = 0, lo = 0;
        if (k < EMBD) {
            float f = sW1[(long)k * HID + c];
            unsigned int u = __float_as_uint(f);
            hi = u >> 16;
            float r = __uint_as_float(u & 0xffff0000u);
            lo = __float_as_uint(f - r) >> 16;
        }
        whi[(long)c * KPAD + k] = (unsigned short)hi;
        wlo[(long)c * KPAD + k] = (unsigned short)lo;
    }
}

// ---------------- compact ids with count > 0 ----------------
__global__ void k_compact(const int* __restrict__ counts, int* __restrict__ cand,
                          int* __restrict__ ccnt, int* __restrict__ ncand) {
    int i = blockIdx.x * blockDim.x + threadIdx.x;
    if (i < VOCABN) {
        int c = counts[i];
        if (c > 0) { int p = atomicAdd(ncand, 1); cand[p] = i; ccnt[p] = c; }
    }
}

// ---------------- MFMA 32x32x16 bf16x3 score + per-block top-10 ----------------
// 256 threads (4 waves). Wave w: rows [32w, 32w+32), all 128 cols (4 tiles).
// C/D: col = lane&31, row = (reg&3) + 8*(reg>>2) + 4*(lane>>5)   [m74/m101]
__global__ __launch_bounds__(256) void k_score(
        const float* __restrict__ emb,
        const unsigned short* __restrict__ whi,
        const unsigned short* __restrict__ wlo,
        const float* __restrict__ qcb,
        const float* __restrict__ sW2,
        const float* __restrict__ sb2,
        const int* __restrict__ counts,
        const int* __restrict__ cand,
        const int* __restrict__ ccnt,
        const int* __restrict__ ncand_p,
        float* __restrict__ taw, int* __restrict__ tai) {
    __shared__ unsigned short WtH[2][HID * WCPAD];   // 18.4 KB
    __shared__ unsigned short WtL[2][HID * WCPAD];   // 18.4 KB
    __shared__ float qcb_s[HID], w2_s[HID], wv[SC_ROWS];
    __shared__ int cid[SC_ROWS], ccn[SC_ROWS];

    const int tid = threadIdx.x;
    const int blk = blockIdx.x;
    const int ncand = cand ? *ncand_p : VOCABN;
    const int base = blk * SC_ROWS;

    if (base >= ncand) {
        if (tid < NTOP) { taw[blk * NTOP + tid] = -1.f; tai[blk * NTOP + tid] = 0x7fffffff; }
        return;
    }
    if (tid < HID) { qcb_s[tid] = qcb[tid]; w2_s[tid] = sW2[tid]; }
    if (tid < SC_ROWS) {
        int i = base + tid;
        int ci = i < ncand ? i : ncand - 1;
        if (cand) { cid[tid] = cand[ci]; ccn[tid] = ccnt[ci]; }
        else      { cid[tid] = ci;       ccn[tid] = counts[ci]; }
    }

    const int lane = tid & 63;
    const int wave = tid >> 6;       // 0..3
    const int lrow = lane & 31;
    const int khalf = lane >> 5;     // 0..1 -> k offset 8*khalf
    const int scol = tid >> 1;       // staging col 0..127
    const int sseg = tid & 1;        // staging k-seg (16 k each)

    f32x16 acc[4];
#pragma unroll
    for (int t = 0; t < 4; ++t)
#pragma unroll
        for (int r = 0; r < 16; ++r) acc[t][r] = 0.f;

    __syncthreads();   // cid ready

    const long erow = (long)cid[wave * 32 + lrow] * EMBD;
    const long EMAX = (long)VOCABN * EMBD - 8;

    // stage W chunk 0
    {
        const long wo = (long)scol * KPAD + sseg * 16;
        u32x4 h0 = *(const u32x4*)&whi[wo];
        u32x4 h1 = *(const u32x4*)&whi[wo + 8];
        u32x4 l0 = *(const u32x4*)&wlo[wo];
        u32x4 l1 = *(const u32x4*)&wlo[wo + 8];
        int la = scol * WCPAD + sseg * 16;
        *(u32x4*)&WtH[0][la] = h0; *(u32x4*)&WtH[0][la + 8] = h1;
        *(u32x4*)&WtL[0][la] = l0; *(u32x4*)&WtL[0][la + 8] = l1;
    }
    // E chunk 0: sub0 k = khalf*8..+7, sub1 k = 16+khalf*8..+7
    long o0 = erow + khalf * 8;        if (o0 > EMAX) o0 = EMAX;
    long o1 = erow + 16 + khalf * 8;   if (o1 > EMAX) o1 = EMAX;
    f32x4 ea0 = *(const f32x4*)&emb[o0];
    f32x4 ea1 = *(const f32x4*)&emb[o0 + 4];
    f32x4 eb0 = *(const f32x4*)&emb[o1];
    f32x4 eb1 = *(const f32x4*)&emb[o1 + 4];
    __syncthreads();

    for (int c = 0; c < NCH; ++c) {
        const int cur = c & 1;
        const bool more = (c + 1 < NCH);
        u32x4 nh0, nh1, nl0, nl1;
        f32x4 na0, na1, nb0, nb1;
        if (more) {   // prefetch next W chunk (regs) + next E frags
            const long wo = (long)scol * KPAD + (c + 1) * WK + sseg * 16;
            nh0 = *(const u32x4*)&whi[wo];
            nh1 = *(const u32x4*)&whi[wo + 8];
            nl0 = *(const u32x4*)&wlo[wo];
            nl1 = *(const u32x4*)&wlo[wo + 8];
            long p0 = erow + (c + 1) * WK + khalf * 8;        if (p0 > EMAX) p0 = EMAX;
            long p1 = erow + (c + 1) * WK + 16 + khalf * 8;   if (p1 > EMAX) p1 = EMAX;
            na0 = *(const f32x4*)&emb[p0];
            na1 = *(const f32x4*)&emb[p0 + 4];
            nb0 = *(const f32x4*)&emb[p1];
            nb1 = *(const f32x4*)&emb[p1 + 4];
        }
        // convert current E to bf16 hi/lo (garbage beyond k=299 is finite; W pad is 0)
        union { bf16x8 v; u32x4 u; } eh[2], el[2];
        split8(ea0, ea1, &eh[0].u, &el[0].u);
        split8(eb0, eb1, &eh[1].u, &el[1].u);

#pragma unroll
        for (int s = 0; s < 2; ++s) {
#pragma unroll
            for (int t = 0; t < 4; ++t) {
                union { bf16x8 v; u32x4 u; } bh, bl;
                int a = (t * 32 + lrow) * WCPAD + s * 16 + khalf * 8;
                bh.u = *(const u32x4*)&WtH[cur][a];
                bl.u = *(const u32x4*)&WtL[cur][a];
                acc[t] = __builtin_amdgcn_mfma_f32_32x32x16_bf16(eh[s].v, bh.v, acc[t], 0, 0, 0);
                acc[t] = __builtin_amdgcn_mfma_f32_32x32x16_bf16(eh[s].v, bl.v, acc[t], 0, 0, 0);
                acc[t] = __builtin_amdgcn_mfma_f32_32x32x16_bf16(el[s].v, bh.v, acc[t], 0, 0, 0);
            }
        }
        if (more) {
            int la = scol * WCPAD + sseg * 16;
            *(u32x4*)&WtH[cur ^ 1][la] = nh0; *(u32x4*)&WtH[cur ^ 1][la + 8] = nh1;
            *(u32x4*)&WtL[cur ^ 1][la] = nl0; *(u32x4*)&WtL[cur ^ 1][la + 8] = nl1;
            ea0 = na0; ea1 = na1; eb0 = nb0; eb1 = nb1;
        }
        __syncthreads();
    }

    // epilogue: relu + W2 dot + 32-lane reduce + sigmoid*count
    const float b2 = sb2[0];
    float pr[16];
#pragma unroll
    for (int r = 0; r < 16; ++r) {
        float s = 0.f;
#pragma unroll
        for (int t = 0; t < 4; ++t) {
            int col = t * 32 + lrow;
            float h = fmaxf(acc[t][r] + qcb_s[col], 0.f);
            s += h * w2_s[col];
        }
        s += __shfl_xor(s, 1); s += __shfl_xor(s, 2);
        s += __shfl_xor(s, 4); s += __shfl_xor(s, 8);
        s += __shfl_xor(s, 16);
        pr[r] = s;
    }
    if (lrow == 0) {
#pragma unroll
        for (int r = 0; r < 16; ++r) {
            int row = wave * 32 + (r & 3) + 8 * (r >> 2) + 4 * khalf;
            float wgt = -1.f;
            if (base + row < ncand)
                wgt = (float)ccn[row] / (1.f + expf(-(pr[r] + b2)));
            wv[row] = wgt;
        }
    }
    __syncthreads();

    // wave 0: top-10 over the 128 row weights (2 per lane)
    if (tid < 64) {
        float w0 = wv[tid], w1 = wv[tid + 64];
        int i0 = (base + tid < ncand) ? cid[tid] : 0x7fffffff;
        int i1 = (base + tid + 64 < ncand) ? cid[tid + 64] : 0x7fffffff;
        for (int r = 0; r < NTOP; ++r) {
            float bw; int bid;
            if (w0 > w1 || (w0 == w1 && i0 < i1)) { bw = w0; bid = i0; }
            else                                   { bw = w1; bid = i1; }
            for (int m = 1; m < 64; m <<= 1) {
                float ow = __shfl_xor(bw, m); int oid = __shfl_xor(bid, m);
                if (ow > bw || (ow == bw && oid < bid)) { bw = ow; bid = oid; }
            }
            if (w0 == bw && i0 == bid)      w0 = -2.f;
            else if (w1 == bw && i1 == bid) w1 = -2.f;
            if (tid == r) { taw[blk * NTOP + r] = bw; tai[blk * NTOP + r] = bid; }
        }
    }
}

// ---------------- top-k helpers ----------------
__device__ __forceinline__ bool tbetter(float w1, int i1, float w2, int i2) {
    return w1 > w2 || (w1 == w2 && i1 < i2);
}

__device__ __forceinline__ void lds_insert(float* mw, int* mid, int t, float w, int id) {
    const int b = t * NTOP;
    if (!tbetter(w, id, mw[b + NTOP - 1], mid[b + NTOP - 1])) return;
    int p = NTOP - 1;
    while (p > 0 && tbetter(w, id, mw[b + p - 1], mid[b + p - 1])) {
        mw[b + p] = mw[b + p - 1]; mid[b + p] = mid[b + p - 1]; --p;
    }
    mw[b + p] = w; mid[b + p] = id;
}

// ---------------- final: global top-10 merge + expansion MLP ----------------
__global__ __launch_bounds__(512) void k_final(const float* __restrict__ taw,
                                               const int* __restrict__ tai,
                                               const float* __restrict__ qctx,
                                               const float* __restrict__ emb,
                                               const float* __restrict__ eW1,
                                               const float* __restrict__ eb1,
                                               const float* __restrict__ eW2,
                                               const float* __restrict__ eb2,
                                               float* __restrict__ out) {
    __shared__ float mw[512 * NTOP];   // 20 KB
    __shared__ int   mid[512 * NTOP];  // 20 KB
    __shared__ int   top_id[NTOP];
    __shared__ float qc[EMBD], em[EMBD], hbuf[HID];
    int t = threadIdx.x;
#pragma unroll
    for (int n = 0; n < NTOP; ++n) { mw[t * NTOP + n] = -1.f; mid[t * NTOP + n] = 0x7fffffff; }
    for (int i = t; i < SC_NBLK * NTOP; i += 512)
        lds_insert(mw, mid, t, taw[i], tai[i]);

    for (int s = 256; s > 0; s >>= 1) {
        __syncthreads();
        if (t < s) {
            const int ta = t * NTOP, tb = (t + s) * NTOP;
            float ow[NTOP]; int oid[NTOP];
            int i = 0, j = 0;
#pragma unroll
            for (int n = 0; n < NTOP; ++n) {
                float wa = mw[ta + i]; int ia = mid[ta + i];
                float wb = mw[tb + j]; int ib = mid[tb + j];
                if (tbetter(wa, ia, wb, ib)) { ow[n] = wa; oid[n] = ia; ++i; }
                else                         { ow[n] = wb; oid[n] = ib; ++j; }
            }
#pragma unroll
            for (int n = 0; n < NTOP; ++n) { mw[ta + n] = ow[n]; mid[ta + n] = oid[n]; }
        }
    }
    __syncthreads();

    if (t < NTOP) {
        top_id[t] = mid[t];
        out[EMBD + t] = (float)mid[t];
        out[EMBD + NTOP + t] = mw[t];
    }
    __syncthreads();

    for (int i = t; i < EMBD; i += 512) {
        float s = 0.f;
        for (int n = 0; n < NTOP; ++n) s += emb[(long)top_id[n] * EMBD + i];
        em[i] = s * (1.0f / NTOP);
        qc[i] = qctx[i];
    }
    __syncthreads();

    // h = relu(feat . eW1 + eb1); 4 threads per col, K split 75
    {
        int col = t >> 2, ks = t & 3;
        float a = 0.f;
        int k0 = ks * 75, k1 = k0 + 75;
        for (int k = k0; k < k1; ++k) {
            float q = qc[k], e = em[k];
            a += q * eW1[(long)k * HID + col];
            a += e * eW1[(long)(EMBD + k) * HID + col];
            a += (q * e) * eW1[(long)(2 * EMBD + k) * HID + col];
        }
        a += __shfl_xor(a, 1);
        a += __shfl_xor(a, 2);
        if (ks == 0) hbuf[col] = fmaxf(a + eb1[col], 0.f);
    }
    __syncthreads();

    for (int i = t; i < EMBD; i += 512) {
        float a = eb2[i];
        for (int j = 0; j < HID; ++j) a += hbuf[j] * eW2[(long)j * EMBD + i];
        out[i] = a;
    }
}

extern "C" void kernel_launch(void* const* d_in, const int* in_sizes, int n_in,
                              void* d_out, int out_size, void* d_ws, size_t ws_size,
                              hipStream_t stream) {
    const int* qterms  = (const int*)d_in[0];
    const int* fdocs   = (const int*)d_in[1];
    const float* emb   = (const float*)d_in[3];
    const float* sW1   = (const float*)d_in[4];
    const float* sb1   = (const float*)d_in[5];
    const float* sW2   = (const float*)d_in[6];
    const float* sb2   = (const float*)d_in[7];
    const float* eW1   = (const float*)d_in[8];
    const float* eb1   = (const float*)d_in[9];
    const float* eW2   = (const float*)d_in[10];
    const float* eb2   = (const float*)d_in[11];
    float* out = (float*)d_out;

    char* ws = (char*)d_ws;
    int*   counts = (int*)ws;                             // 400000
    int*   ncand  = (int*)(ws + 400000);                  // 4 (zeroed with counts)
    float* qctx   = (float*)(ws + 400064);                // 1200
    float* qcb    = (float*)(ws + 401280);                // 512
    float* taw    = (float*)(ws + 401792);                // 782*10*4 = 31280
    int*   tai    = (int*)(ws + 433088);                  // 31280
    unsigned short* whi = (unsigned short*)(ws + 464384); // 128*320*2 = 81920
    unsigned short* wlo = (unsigned short*)(ws + 546304); // 81920
    int* cand = nullptr; int* ccnt = nullptr;
    const bool use_compact = ws_size >= 1428224;
    if (use_compact) {
        cand = (int*)(ws + 628224);                       // 400000
        ccnt = (int*)(ws + 1028224);                      // 400000
    }

    int nflat = in_sizes[1];
    int hblocks = (nflat + 255) / 256;
    int wtblocks = (HID * KPAD + 255) / 256;              // 160

    hipMemsetAsync(ws, 0, 400064, stream);                // counts + ncand
    k_pre<<<hblocks + 1 + wtblocks, 256, 0, stream>>>(qterms, fdocs, nflat, hblocks,
                                                      emb, sW1, sb1, counts, qctx, qcb, whi, wlo);
    if (use_compact)
        k_compact<<<(VOCABN + 255) / 256, 256, 0, stream>>>(counts, cand, ccnt, ncand);
    k_score<<<SC_NBLK, 256, 0, stream>>>(emb, whi, wlo, qcb, sW2, sb2,
                                         counts, cand, ccnt, ncand, taw, tai);
    k_final<<<1, 512, 0, stream>>>(taw, tai, qctx, emb, eW1, eb1, eW2, eb2, out);
}